// Round 11
// baseline (250.875 us; speedup 1.0000x reference)
//
#include <hip/hip_runtime.h>
#include <math.h>

// ---------------------------------------------------------------------------
// EncoderGPECls: kNN(16) -> PCA curvature blend -> adaptive GPE embeddings
// xyz: [8,4096,3] f32  ->  out: [8,4096,128] f32
//
// R23 = R20 skeleton with the candidate stream moved to the SCALAR pipe.
//   R22 null: sched_barrier didn't materialize the VGPR pipeline (VGPR=52);
//   LDS-broadcast stream + lgkmcnt stalls cap knn at ~198us.
//   The stream is wave-uniform -> s_load via readfirstlane-uniform pointer
//   from the read-only raw xyz buffer: stream leaves the LDS pipe AND the
//   VALU address arithmetic (SALU does the addressing; SMEM issues parallel
//   to VALU). Ladder consumes candidates as SGPR operands (max-1-SGPR rule:
//   v_sub + fma chain). Ping-pong 4-cand groups: the per-group lgkmcnt
//   drain lands after ~232cyc of compute on the other group, so latency
//   overlaps even with out-of-order SMEM full-drain semantics.
//   d2 chain = R12's raw d2f EVERYWHERE (tile stores raw (x,y,z,0); drains/
//   merges/epilogue use the same IEEE chain; keys = uint(d2)<<32|ix, d2>=0)
//   -> selection semantics identical to the R12/R20 proven path.
//   Engagement signature: SQ_LDS_BANK_CONFLICT collapses (<0.3M).
//   Everything else byte-identical to R20 (session best, 244.8us).
//
// ws float layout:
//   [0, 32768)            curv per point
//   [32768, 131072)       rasig2 (3 SoA planes of 32768)
//   [131072, 131584)      curv partial sums [b][chunk] (8 x 64)
//   [131584, 131680)      per-batch raw sums as 48 DOUBLES
// ---------------------------------------------------------------------------

#define NPTS 4096
#define KNN 17          // 16 neighbors + self (self contributes zero to sums)
#define BLKT 512        // 8 waves; 64 queries per block (1 per lane)
#define QPB 64
#define ESIZE 512       // candidates per wave (eighth)
#define SEG 256         // pass-2 segment size (u8 offsets)
#define SCAP 17         // survivor slots per lane per segment

#define WS_CURV  0
#define WS_RAS2  32768
#define WS_CSUM  131072
#define WS_STAT  131584

typedef unsigned long long ull;
#define SENT 0x7F800000FFFFFFFFULL   // (+inf bits, idx=max) sentinel key

#define SBAR() __builtin_amdgcn_sched_barrier(0)

// THE single d2 definition: explicit fmaf chain, identical IEEE ops at every
// call site (R12's proven chain; d2 >= 0 always).
__device__ __forceinline__ float d2f(float qx, float qy, float qz,
                                     float cx, float cy, float cz) {
    float dx = qx - cx, dy = qy - cy, dz = qz - cz;
    return __builtin_fmaf(dz, dz, __builtin_fmaf(dy, dy, dx * dx));
}

// predicated replace-max insert of packed (d2bits<<32|idx) key
__device__ __forceinline__ void insertp(ull v, bool ins, ull (&md)[KNN],
                                        ull& maxv, int& maxp) {
#pragma unroll
    for (int k = 0; k < KNN; k++) {
        bool sel = ins && (k == maxp);
        md[k] = sel ? v : md[k];
    }
    maxv = md[0]; maxp = 0;
#pragma unroll
    for (int k = 1; k < KNN; k++) {
        bool g = md[k] > maxv;
        maxv = g ? md[k] : maxv;
        maxp = g ? k : maxp;
    }
}

// ---------------- 3x3 symmetric eigensolve (double, trig method) -----------
__device__ __forceinline__ float curv_from_cov(float c00, float c01, float c02,
                                               float c11, float c12, float c22) {
    double a00 = c00, a01 = c01, a02 = c02, a11 = c11, a12 = c12, a22 = c22;
    double tr = a00 + a11 + a22;
    double q  = tr * (1.0 / 3.0);
    double b00 = a00 - q, b11 = a11 - q, b22 = a22 - q;
    double p2 = b00 * b00 + b11 * b11 + b22 * b22
              + 2.0 * (a01 * a01 + a02 * a02 + a12 * a12);
    double lmin;
    if (p2 < 1e-60) {
        lmin = q;
    } else {
        double p  = sqrt(p2 * (1.0 / 6.0));
        double ip = 1.0 / p;
        double m00 = b00 * ip, m11 = b11 * ip, m22 = b22 * ip;
        double m01 = a01 * ip, m02 = a02 * ip, m12 = a12 * ip;
        double det = m00 * (m11 * m22 - m12 * m12)
                   - m01 * (m01 * m22 - m12 * m02)
                   + m02 * (m01 * m12 - m11 * m02);
        double r = 0.5 * det;
        r = r > 1.0 ? 1.0 : (r < -1.0 ? -1.0 : r);
        double phi = acos(r) * (1.0 / 3.0);
        lmin = q + 2.0 * p * cos(phi + 2.0943951023931953);
    }
    return (float)(lmin / (tr + 1e-6));
}

// ---------------- kNN + covariance + curvature + lstd ----------------------
__global__ __launch_bounds__(BLKT, 4) void knn_kernel(const float* __restrict__ xyz,
                                                      float* __restrict__ ws) {
    __shared__ float4 pts[NPTS];                 // 64 KB raw (x,y,z,0) tile
    __shared__ ull aux[1088];                    // 8704 B arena (aliased)
    unsigned char* sbuf = (unsigned char*)aux;   // [SCAP][BLKT] u8 survivors
    unsigned short* pub = (unsigned short*)aux;  // 4 regions x 64x17 u16 idx
    int b = blockIdx.x >> 6;                     // 64 blocks per batch
    int chunk = blockIdx.x & 63;
    int tid = threadIdx.x;
    const float* base = xyz + b * NPTS * 3;
    for (int p = tid; p < NPTS; p += BLKT) {
        pts[p] = make_float4(base[p * 3], base[p * 3 + 1], base[p * 3 + 2], 0.0f);
    }
    __syncthreads();

    // ---- chunk-0 block computes per-batch raw sums in double (into aux) ----
    if (chunk == 0) {
        double sx = 0, sy = 0, sz = 0, qxx = 0, qyy = 0, qzz = 0;
        for (int p = tid; p < NPTS; p += BLKT) {
            float4 c = pts[p];
            sx += (double)c.x; sy += (double)c.y; sz += (double)c.z;
            qxx += (double)c.x * c.x; qyy += (double)c.y * c.y; qzz += (double)c.z * c.z;
        }
        for (int off = 32; off > 0; off >>= 1) {
            sx += __shfl_down(sx, off);  sy += __shfl_down(sy, off);
            sz += __shfl_down(sz, off);  qxx += __shfl_down(qxx, off);
            qyy += __shfl_down(qyy, off); qzz += __shfl_down(qzz, off);
        }
        double* dstat = (double*)aux;
        int wid = tid >> 6;
        if ((tid & 63) == 0) {
            dstat[wid * 6 + 0] = sx;  dstat[wid * 6 + 1] = sy;  dstat[wid * 6 + 2] = sz;
            dstat[wid * 6 + 3] = qxx; dstat[wid * 6 + 4] = qyy; dstat[wid * 6 + 5] = qzz;
        }
        __syncthreads();
        if (tid == 0) {
            double* wd = (double*)(ws + WS_STAT);
            for (int qq = 0; qq < 6; qq++) {
                double a = 0.0;
                for (int w = 0; w < 8; w++) a += dstat[w * 6 + qq];
                wd[b * 6 + qq] = a;
            }
        }
        __syncthreads();                         // aux free for survivor use
    }

    int wv = tid >> 6;                           // wave id: candidate eighth
    int lane = tid & 63;
    int i = chunk * QPB + lane;                  // this lane's query point
    float4 qc = pts[i];
    float qx = qc.x, qy = qc.y, qz = qc.z;
    int cbase = wv * ESIZE;                      // this wave's candidate range
    // wave-uniform scalar pointer to this wave's raw candidate floats
    const float* cbs = base + (size_t)__builtin_amdgcn_readfirstlane(wv) * (ESIZE * 3);

    // scalar-group load: 4 candidates = 12 contiguous dwords (uniform addr)
#define LOADG(PX, PY, PZ, bm) { _Pragma("unroll") \
    for (int u = 0; u < 4; u++) { \
        PX[u] = cbs[((bm) + u) * 3 + 0]; \
        PY[u] = cbs[((bm) + u) * 3 + 1]; \
        PZ[u] = cbs[((bm) + u) * 3 + 2]; } }

    // ---- pass 1: med3 top-17 ladder over the scalar stream ----------------
    float md[KNN];
#pragma unroll
    for (int k = 0; k < KNN; k++) md[k] = 3.4e38f;

#define LADDER(cx, cy, cz) { \
    float d2 = d2f(qx, qy, qz, (cx), (cy), (cz)); \
    _Pragma("unroll") \
    for (int k = KNN - 1; k >= 1; k--) \
        md[k] = __builtin_amdgcn_fmed3f(d2, md[k - 1], md[k]); \
    md[0] = fminf(d2, md[0]); }

    {
        float Ax[4], Ay[4], Az[4], Bx[4], By[4], Bz[4];
        LOADG(Ax, Ay, Az, 0); SBAR();
        for (int m = 0; m < ESIZE - 8; m += 8) {
            LOADG(Bx, By, Bz, m + 4); SBAR();    // B in flight over ladder(A)
#pragma unroll
            for (int u = 0; u < 4; u++) LADDER(Ax[u], Ay[u], Az[u]);
            LOADG(Ax, Ay, Az, m + 8); SBAR();    // A' in flight over ladder(B)
#pragma unroll
            for (int u = 0; u < 4; u++) LADDER(Bx[u], By[u], Bz[u]);
        }
        LOADG(Bx, By, Bz, ESIZE - 4); SBAR();
#pragma unroll
        for (int u = 0; u < 4; u++) LADDER(Ax[u], Ay[u], Az[u]);
#pragma unroll
        for (int u = 0; u < 4; u++) LADDER(Bx[u], By[u], Bz[u]);
    }
#undef LADDER
    float tau = md[KNN - 1];   // exact 17th (identical d2f chain everywhere)

    // ---- pass 2 (2 segments of 256): u8 survivors from the scalar stream --
    ull k17[KNN];
#pragma unroll
    for (int k = 0; k < KNN; k++) k17[k] = SENT;
    ull maxv = SENT; int maxp = 0;

#define P2BODY(cx, cy, cz, off) { \
    float d2 = d2f(qx, qy, qz, (cx), (cy), (cz)); \
    if (d2 <= tau) {                    /* clamp drops latest tie = jax */ \
        if (cnt < SCAP) sbuf[cnt * BLKT + tid] = (unsigned char)(off); \
        cnt++; } }

#pragma unroll
    for (int sgi = 0; sgi < 2; sgi++) {
        int segbase = cbase + sgi * SEG;
        const float* sbs = cbs + sgi * (SEG * 3);        // uniform
        int cnt = 0;
        {
            float Ax[4], Ay[4], Az[4], Bx[4], By[4], Bz[4];
#define LOADS(PX, PY, PZ, bm) { _Pragma("unroll") \
    for (int u = 0; u < 4; u++) { \
        PX[u] = sbs[((bm) + u) * 3 + 0]; \
        PY[u] = sbs[((bm) + u) * 3 + 1]; \
        PZ[u] = sbs[((bm) + u) * 3 + 2]; } }
            LOADS(Ax, Ay, Az, 0); SBAR();
            for (int m = 0; m < SEG - 8; m += 8) {
                LOADS(Bx, By, Bz, m + 4); SBAR();
#pragma unroll
                for (int u = 0; u < 4; u++) P2BODY(Ax[u], Ay[u], Az[u], m + u);
                LOADS(Ax, Ay, Az, m + 8); SBAR();
#pragma unroll
                for (int u = 0; u < 4; u++) P2BODY(Bx[u], By[u], Bz[u], m + 4 + u);
            }
            LOADS(Bx, By, Bz, SEG - 4); SBAR();
#pragma unroll
            for (int u = 0; u < 4; u++) P2BODY(Ax[u], Ay[u], Az[u], SEG - 8 + u);
#pragma unroll
            for (int u = 0; u < 4; u++) P2BODY(Bx[u], By[u], Bz[u], SEG - 4 + u);
#undef LOADS
        }
        // drain this segment's survivors into the exact u64 top-17 (LDS tile)
#pragma unroll
        for (int t = 0; t < SCAP; t++) {
            if (__any(t < cnt)) {
                int ix = segbase + sbuf[t * BLKT + tid];
                float4 c = pts[ix];
                float d2 = d2f(qx, qy, qz, c.x, c.y, c.z);
                ull key = ((ull)__float_as_uint(d2) << 32) | (unsigned)ix;
                bool ins = (t < cnt) && (key < maxv);
                if (__any(ins)) insertp(key, ins, k17, maxv, maxp);
            }
        }
    }
#undef P2BODY
#undef LOADG

    // ---- 3-round tournament merge (u16 idx publish, keys rebuilt exactly) --
    // regions: r * 1088 u16 entries, entry lane*17+k
    __syncthreads();
    if (wv & 1) {
#pragma unroll
        for (int k = 0; k < KNN; k++)
            pub[(wv >> 1) * 1088 + lane * KNN + k] = (unsigned short)(k17[k] & 0xffffULL);
    }
    __syncthreads();
    if (!(wv & 1)) {
        int r = wv >> 1;
#pragma unroll
        for (int k = 0; k < KNN; k++) {
            int ix = pub[r * 1088 + lane * KNN + k];
            float4 c = pts[ix];
            float d2 = d2f(qx, qy, qz, c.x, c.y, c.z);
            ull key = ((ull)__float_as_uint(d2) << 32) | (unsigned)ix;
            bool ins = key < maxv;
            if (__any(ins)) insertp(key, ins, k17, maxv, maxp);
        }
    }
    // round 2: 2->0, 6->4 (regions 0,1)
    __syncthreads();
    if (wv == 2 || wv == 6) {
#pragma unroll
        for (int k = 0; k < KNN; k++)
            pub[(wv >> 2) * 1088 + lane * KNN + k] = (unsigned short)(k17[k] & 0xffffULL);
    }
    __syncthreads();
    if (wv == 0 || wv == 4) {
        int r = wv >> 2;
#pragma unroll
        for (int k = 0; k < KNN; k++) {
            int ix = pub[r * 1088 + lane * KNN + k];
            float4 c = pts[ix];
            float d2 = d2f(qx, qy, qz, c.x, c.y, c.z);
            ull key = ((ull)__float_as_uint(d2) << 32) | (unsigned)ix;
            bool ins = key < maxv;
            if (__any(ins)) insertp(key, ins, k17, maxv, maxp);
        }
    }
    // round 3: 4->0 (region 0)
    __syncthreads();
    if (wv == 4) {
#pragma unroll
        for (int k = 0; k < KNN; k++)
            pub[lane * KNN + k] = (unsigned short)(k17[k] & 0xffffULL);
    }
    __syncthreads();

    // ---- epilogue on wave 0: final merge + moments -> curv, rasig2 --------
    if (wv == 0) {
#pragma unroll
        for (int k = 0; k < KNN; k++) {
            int ix = pub[lane * KNN + k];
            float4 c = pts[ix];
            float d2 = d2f(qx, qy, qz, c.x, c.y, c.z);
            ull key = ((ull)__float_as_uint(d2) << 32) | (unsigned)ix;
            bool ins = key < maxv;
            if (__any(ins)) insertp(key, ins, k17, maxv, maxp);
        }

        float s1x = 0, s1y = 0, s1z = 0;
        float cxx = 0, cxy = 0, cxz = 0, cyy = 0, cyz = 0, czz = 0;
#pragma unroll
        for (int k = 0; k < KNN; k++) {
            int j = (int)(k17[k] & 0xffffffffULL);
            float4 c = pts[j];
            float ux = c.x - qx, uy = c.y - qy, uz = c.z - qz;
            s1x += ux; s1y += uy; s1z += uz;
            cxx += ux * ux; cxy += ux * uy; cxz += ux * uz;
            cyy += uy * uy; cyz += uy * uz; czz += uz * uz;
        }
        const float i16 = 1.0f / 16.0f, i15 = 1.0f / 15.0f;
        float mx = s1x * i16, my = s1y * i16, mz = s1z * i16;
        float c00 = (cxx - 16.0f * mx * mx) * i15;
        float c01 = (cxy - 16.0f * mx * my) * i15;
        float c02 = (cxz - 16.0f * mx * mz) * i15;
        float c11 = (cyy - 16.0f * my * my) * i15;
        float c12 = (cyz - 16.0f * my * mz) * i15;
        float c22 = (czz - 16.0f * mz * mz) * i15;

        float curv = curv_from_cov(c00, c01, c02, c11, c12, c22);

        float v0 = c00 > 0.0f ? c00 : 0.0f;
        float v1 = c11 > 0.0f ? c11 : 0.0f;
        float v2 = c22 > 0.0f ? c22 : 0.0f;
        float r2x = 1.0f / (0.3f * (1.0f + sqrtf(v0)) + 1e-6f);
        float r2y = 1.0f / (0.3f * (1.0f + sqrtf(v1)) + 1e-6f);
        float r2z = 1.0f / (0.3f * (1.0f + sqrtf(v2)) + 1e-6f);

        int g = b * NPTS + i;
        ws[WS_CURV + g] = curv;
        ws[WS_RAS2 + 0 * 32768 + g] = r2x;
        ws[WS_RAS2 + 1 * 32768 + g] = r2y;
        ws[WS_RAS2 + 2 * 32768 + g] = r2z;

        // non-atomic per-(b,chunk) partial sum
        float cs = curv;
        for (int off = 32; off > 0; off >>= 1) cs += __shfl_down(cs, off);
        if (lane == 0) ws[WS_CSUM + b * 64 + chunk] = cs;
    }
}

// ---------------- final embedding (lean prefix, float4 stores) -------------
__global__ void out_kernel(const float* __restrict__ xyz,
                           const float* __restrict__ ws,
                           float* __restrict__ out) {
    __shared__ float sc[3];                      // rasig1, blend, 1-blend
    __shared__ float scm[8];                     // per-batch curv mean
    if (threadIdx.x < 64) {
        // gstd from double stats (24 lanes) -> sigmoid scalars
        float part = 0.0f;
        if (threadIdx.x < 24) {
            const double* st = (const double*)(ws + WS_STAT);
            int bb = threadIdx.x / 3, dd = threadIdx.x % 3;
            double s = st[bb * 6 + dd], ss = st[bb * 6 + 3 + dd];
            double var = (ss - s * s / 4096.0) / 4095.0;
            part = (float)sqrt(var > 0.0 ? var : 0.0);
        }
        float p2 = part;
        for (int off = 32; off > 0; off >>= 1) p2 += __shfl_down(p2, off);
        if (threadIdx.x == 0) {
            float gf = p2 * (1.0f / 24.0f);
            float denom = 0.3f * (1.0f + gf) + 1e-6f;
            float blend = 1.0f / (1.0f + __expf(-(gf - 0.1f) * 10.0f));
            sc[0] = 1.0f / denom;
            sc[1] = blend;
            sc[2] = 1.0f - blend;
        }
        // per-batch curv means from 512 partials: lane L sums [L*8, L*8+8)
        float cp = 0.0f;
        const float* pf = ws + WS_CSUM;
#pragma unroll
        for (int t = 0; t < 8; t++) cp += pf[threadIdx.x * 8 + t];
        cp += __shfl_down(cp, 4);
        cp += __shfl_down(cp, 2);
        cp += __shfl_down(cp, 1);
        if ((threadIdx.x & 7) == 0) scm[threadIdx.x >> 3] = cp * (1.0f / 4096.0f);
    }
    __syncthreads();

    int q4 = blockIdx.x * 256 + (int)threadIdx.x;     // quad id (4 outputs)
    int j0 = (q4 & 31) << 2;                          // 32 quads per point
    int g  = q4 >> 5;
    int b  = g >> 12;
    float rasig1 = sc[0];
    float blend  = sc[1];
    float blendc = sc[2];
    float curv   = ws[WS_CURV + g];
    float w = 1.0f / (1.0f + __expf(-10.0f * (curv - scm[b])));
    float wc = 1.0f - w;

    float o[4];
#pragma unroll
    for (int e = 0; e < 4; e++) {
        int j = j0 + e;
        int f = (j < 127) ? j : 128;                  // OUT_IDX
        int d = (f >= 86) ? 2 : ((f >= 43) ? 1 : 0);
        int t = f - d * 43;
        float fv = (float)((double)(t + 1) * (2.0 / 44.0) - 1.0);  // FEAT_VAL
        float x = xyz[g * 3 + d];
        float t1 = (x - fv) * rasig1;
        float e1 = blend * __expf(-0.5f * t1 * t1) + blendc * __cosf(t1);
        float t2 = (x - fv) * ws[WS_RAS2 + (d << 15) + g];
        float e2 = __expf(-0.5f * t2 * t2);
        o[e] = w * e1 + wc * e2;
    }
    *(float4*)(out + ((long)q4 << 2)) = make_float4(o[0], o[1], o[2], o[3]);
}

extern "C" void kernel_launch(void* const* d_in, const int* in_sizes, int n_in,
                              void* d_out, int out_size, void* d_ws, size_t ws_size,
                              hipStream_t stream) {
    const float* xyz = (const float*)d_in[0];
    float* out = (float*)d_out;
    float* ws = (float*)d_ws;

    knn_kernel<<<512, BLKT, 0, stream>>>(xyz, ws);
    // each block writes 256 threads x 4 floats = 1024 floats
    out_kernel<<<out_size / 1024, 256, 0, stream>>>(xyz, ws, out);
}

// Round 12
// 250.777 us; speedup vs baseline: 1.0004x; 1.0004x over previous
//
#include <hip/hip_runtime.h>
#include <math.h>

// ---------------------------------------------------------------------------
// EncoderGPECls: kNN(16) -> PCA curvature blend -> adaptive GPE embeddings
// xyz: [8,4096,3] f32  ->  out: [8,4096,128] f32
//
// R24 = R20 skeleton + SoA 3-plane LDS tile (25% fewer stream ds_reads).
//   R23 post-mortem: scalar-pipe didn't engage (conflicts rose, VALU rose);
//   R20 remains best (244.8 = knn 198 + out ~6 + ~40us fixed overhead).
//   Remaining slack: per-group stall ~1600cyc >> any one read's latency;
//   the untried lever is the LDS-READ COUNT itself (broadcast return moves
//   64x16B per instr). SoA X/Y/Z planes serve 4 candidates per 3 b128
//   (w-component dropped by reverting to R12's raw d2f chain -- R15 proved
//   VALU count is free, so +3 VALU/cand costs nothing).
//   Tile 48KB + 8.7KB arena = 57.9KB -> 2 blocks/CU unchanged.
//   Pass 1: 8-cand ping-pong groups (6 loads, was 8). Pass 2: 4-cand
//   groups (3 loads, was 4). ALL d2 sites (scan/drain/merge/epilogue) use
//   the identical raw d2f fmaf chain; keys = uint(d2)<<32|ix, SENT =
//   (+inf,idxmax) -- the R12-proven selection semantics (exact tau, SCAP
//   clamp drops latest tie = jax drop, lower-index tie-break).
//   Null result (knn 195-210) marks ~198 as this structure's floor.
//
// ws float layout:
//   [0, 32768)            curv per point
//   [32768, 131072)       rasig2 (3 SoA planes of 32768)
//   [131072, 131584)      curv partial sums [b][chunk] (8 x 64)
//   [131584, 131680)      per-batch raw sums as 48 DOUBLES
// ---------------------------------------------------------------------------

#define NPTS 4096
#define KNN 17          // 16 neighbors + self (self contributes zero to sums)
#define BLKT 512        // 8 waves; 64 queries per block (1 per lane)
#define QPB 64
#define ESIZE 512       // candidates per wave (eighth)
#define SEG 256         // pass-2 segment size (u8 offsets)
#define SCAP 17         // survivor slots per lane per segment

#define WS_CURV  0
#define WS_RAS2  32768
#define WS_CSUM  131072
#define WS_STAT  131584

typedef unsigned long long ull;
#define SENT 0x7F800000FFFFFFFFULL   // (+inf bits, idx=max) sentinel key

// THE single d2 definition: explicit fmaf chain, identical IEEE ops at every
// call site (R12's proven chain; d2 >= 0 always).
__device__ __forceinline__ float d2f(float qx, float qy, float qz,
                                     float cx, float cy, float cz) {
    float dx = qx - cx, dy = qy - cy, dz = qz - cz;
    return __builtin_fmaf(dz, dz, __builtin_fmaf(dy, dy, dx * dx));
}

// predicated replace-max insert of packed (d2bits<<32|idx) key
__device__ __forceinline__ void insertp(ull v, bool ins, ull (&md)[KNN],
                                        ull& maxv, int& maxp) {
#pragma unroll
    for (int k = 0; k < KNN; k++) {
        bool sel = ins && (k == maxp);
        md[k] = sel ? v : md[k];
    }
    maxv = md[0]; maxp = 0;
#pragma unroll
    for (int k = 1; k < KNN; k++) {
        bool g = md[k] > maxv;
        maxv = g ? md[k] : maxv;
        maxp = g ? k : maxp;
    }
}

// ---------------- 3x3 symmetric eigensolve (double, trig method) -----------
__device__ __forceinline__ float curv_from_cov(float c00, float c01, float c02,
                                               float c11, float c12, float c22) {
    double a00 = c00, a01 = c01, a02 = c02, a11 = c11, a12 = c12, a22 = c22;
    double tr = a00 + a11 + a22;
    double q  = tr * (1.0 / 3.0);
    double b00 = a00 - q, b11 = a11 - q, b22 = a22 - q;
    double p2 = b00 * b00 + b11 * b11 + b22 * b22
              + 2.0 * (a01 * a01 + a02 * a02 + a12 * a12);
    double lmin;
    if (p2 < 1e-60) {
        lmin = q;
    } else {
        double p  = sqrt(p2 * (1.0 / 6.0));
        double ip = 1.0 / p;
        double m00 = b00 * ip, m11 = b11 * ip, m22 = b22 * ip;
        double m01 = a01 * ip, m02 = a02 * ip, m12 = a12 * ip;
        double det = m00 * (m11 * m22 - m12 * m12)
                   - m01 * (m01 * m22 - m12 * m02)
                   + m02 * (m01 * m12 - m11 * m02);
        double r = 0.5 * det;
        r = r > 1.0 ? 1.0 : (r < -1.0 ? -1.0 : r);
        double phi = acos(r) * (1.0 / 3.0);
        lmin = q + 2.0 * p * cos(phi + 2.0943951023931953);
    }
    return (float)(lmin / (tr + 1e-6));
}

// ---------------- kNN + covariance + curvature + lstd ----------------------
__global__ __launch_bounds__(BLKT, 4) void knn_kernel(const float* __restrict__ xyz,
                                                      float* __restrict__ ws) {
    __shared__ float Xs[NPTS];                   // 16 KB  SoA planes
    __shared__ float Ys[NPTS];                   // 16 KB
    __shared__ float Zs[NPTS];                   // 16 KB
    __shared__ ull aux[1088];                    // 8704 B arena (aliased)
    unsigned char* sbuf = (unsigned char*)aux;   // [SCAP][BLKT] u8 survivors
    unsigned short* pub = (unsigned short*)aux;  // 4 regions x 64x17 u16 idx
    int b = blockIdx.x >> 6;                     // 64 blocks per batch
    int chunk = blockIdx.x & 63;
    int tid = threadIdx.x;
    const float* base = xyz + b * NPTS * 3;
    for (int p = tid; p < NPTS; p += BLKT) {
        Xs[p] = base[p * 3 + 0];
        Ys[p] = base[p * 3 + 1];
        Zs[p] = base[p * 3 + 2];
    }
    __syncthreads();

    // ---- chunk-0 block computes per-batch raw sums in double (into aux) ----
    if (chunk == 0) {
        double sx = 0, sy = 0, sz = 0, qxx = 0, qyy = 0, qzz = 0;
        for (int p = tid; p < NPTS; p += BLKT) {
            float x = Xs[p], y = Ys[p], z = Zs[p];
            sx += (double)x; sy += (double)y; sz += (double)z;
            qxx += (double)x * x; qyy += (double)y * y; qzz += (double)z * z;
        }
        for (int off = 32; off > 0; off >>= 1) {
            sx += __shfl_down(sx, off);  sy += __shfl_down(sy, off);
            sz += __shfl_down(sz, off);  qxx += __shfl_down(qxx, off);
            qyy += __shfl_down(qyy, off); qzz += __shfl_down(qzz, off);
        }
        double* dstat = (double*)aux;
        int wid = tid >> 6;
        if ((tid & 63) == 0) {
            dstat[wid * 6 + 0] = sx;  dstat[wid * 6 + 1] = sy;  dstat[wid * 6 + 2] = sz;
            dstat[wid * 6 + 3] = qxx; dstat[wid * 6 + 4] = qyy; dstat[wid * 6 + 5] = qzz;
        }
        __syncthreads();
        if (tid == 0) {
            double* wd = (double*)(ws + WS_STAT);
            for (int qq = 0; qq < 6; qq++) {
                double a = 0.0;
                for (int w = 0; w < 8; w++) a += dstat[w * 6 + qq];
                wd[b * 6 + qq] = a;
            }
        }
        __syncthreads();                         // aux free for survivor use
    }

    int wv = tid >> 6;                           // wave id: candidate eighth
    int lane = tid & 63;
    int i = chunk * QPB + lane;                  // this lane's query point
    float qx = Xs[i], qy = Ys[i], qz = Zs[i];
    int cbase = wv * ESIZE;                      // this wave's candidate range
    const float4* Xv = (const float4*)(Xs + cbase);   // 16B-aligned (cbase%4==0)
    const float4* Yv = (const float4*)(Ys + cbase);
    const float4* Zv = (const float4*)(Zs + cbase);

    // 8-candidate SoA group load: 6 x ds_read_b128 (g = m>>2)
#define LOADG8(AX, AY, AZ, g) { \
    *(float4*)&AX[0] = Xv[(g)]; *(float4*)&AX[4] = Xv[(g) + 1]; \
    *(float4*)&AY[0] = Yv[(g)]; *(float4*)&AY[4] = Yv[(g) + 1]; \
    *(float4*)&AZ[0] = Zv[(g)]; *(float4*)&AZ[4] = Zv[(g) + 1]; }

    // ---- pass 1: med3 top-17 ladder, depth-8 ping-pong, SoA stream --------
    float md[KNN];
#pragma unroll
    for (int k = 0; k < KNN; k++) md[k] = 3.4e38f;

#define LADDER(cx, cy, cz) { \
    float d2 = d2f(qx, qy, qz, (cx), (cy), (cz)); \
    _Pragma("unroll") \
    for (int k = KNN - 1; k >= 1; k--) \
        md[k] = __builtin_amdgcn_fmed3f(d2, md[k - 1], md[k]); \
    md[0] = fminf(d2, md[0]); }

    {
        float Ax[8], Ay[8], Az[8], Bx[8], By[8], Bz[8];
        LOADG8(Ax, Ay, Az, 0);
        for (int m = 0; m < ESIZE - 16; m += 16) {
            LOADG8(Bx, By, Bz, (m >> 2) + 2);    // B in flight over ladder(A)
#pragma unroll
            for (int u = 0; u < 8; u++) LADDER(Ax[u], Ay[u], Az[u]);
            LOADG8(Ax, Ay, Az, (m >> 2) + 4);    // A' in flight over ladder(B)
#pragma unroll
            for (int u = 0; u < 8; u++) LADDER(Bx[u], By[u], Bz[u]);
        }
        // tail: A = [ESIZE-16, ESIZE-8)
        LOADG8(Bx, By, Bz, (ESIZE - 8) >> 2);
#pragma unroll
        for (int u = 0; u < 8; u++) LADDER(Ax[u], Ay[u], Az[u]);
#pragma unroll
        for (int u = 0; u < 8; u++) LADDER(Bx[u], By[u], Bz[u]);
    }
#undef LADDER
    float tau = md[KNN - 1];   // exact 17th (identical d2f chain everywhere)

    // ---- pass 2 (2 segments of 256): u8 survivors, depth-4, SoA stream ----
    ull k17[KNN];
#pragma unroll
    for (int k = 0; k < KNN; k++) k17[k] = SENT;
    ull maxv = SENT; int maxp = 0;

#define P2BODY(cx, cy, cz, off) { \
    float d2 = d2f(qx, qy, qz, (cx), (cy), (cz)); \
    if (d2 <= tau) {                    /* clamp drops latest tie = jax */ \
        if (cnt < SCAP) sbuf[cnt * BLKT + tid] = (unsigned char)(off); \
        cnt++; } }

#define LOADS4(AX, AY, AZ, g) { \
    *(float4*)&AX[0] = Xs4[(g)]; \
    *(float4*)&AY[0] = Ys4[(g)]; \
    *(float4*)&AZ[0] = Zs4[(g)]; }

#pragma unroll
    for (int sgi = 0; sgi < 2; sgi++) {
        int segbase = cbase + sgi * SEG;
        const float4* Xs4 = (const float4*)(Xs + segbase);
        const float4* Ys4 = (const float4*)(Ys + segbase);
        const float4* Zs4 = (const float4*)(Zs + segbase);
        int cnt = 0;
        {
            float Ax[4], Ay[4], Az[4], Bx[4], By[4], Bz[4];
            LOADS4(Ax, Ay, Az, 0);
            for (int m = 0; m < SEG - 8; m += 8) {
                LOADS4(Bx, By, Bz, (m >> 2) + 1);
#pragma unroll
                for (int u = 0; u < 4; u++) P2BODY(Ax[u], Ay[u], Az[u], m + u);
                LOADS4(Ax, Ay, Az, (m >> 2) + 2);
#pragma unroll
                for (int u = 0; u < 4; u++) P2BODY(Bx[u], By[u], Bz[u], m + 4 + u);
            }
            LOADS4(Bx, By, Bz, (SEG - 4) >> 2);
#pragma unroll
            for (int u = 0; u < 4; u++) P2BODY(Ax[u], Ay[u], Az[u], SEG - 8 + u);
#pragma unroll
            for (int u = 0; u < 4; u++) P2BODY(Bx[u], By[u], Bz[u], SEG - 4 + u);
        }
        // drain this segment's survivors into the exact u64 top-17
#pragma unroll
        for (int t = 0; t < SCAP; t++) {
            if (__any(t < cnt)) {
                int ix = segbase + sbuf[t * BLKT + tid];
                float d2 = d2f(qx, qy, qz, Xs[ix], Ys[ix], Zs[ix]);
                ull key = ((ull)__float_as_uint(d2) << 32) | (unsigned)ix;
                bool ins = (t < cnt) && (key < maxv);
                if (__any(ins)) insertp(key, ins, k17, maxv, maxp);
            }
        }
    }
#undef P2BODY
#undef LOADS4
#undef LOADG8

    // ---- 3-round tournament merge (u16 idx publish, keys rebuilt exactly) --
    // regions: r * 1088 u16 entries, entry lane*17+k
    __syncthreads();
    if (wv & 1) {
#pragma unroll
        for (int k = 0; k < KNN; k++)
            pub[(wv >> 1) * 1088 + lane * KNN + k] = (unsigned short)(k17[k] & 0xffffULL);
    }
    __syncthreads();
    if (!(wv & 1)) {
        int r = wv >> 1;
#pragma unroll
        for (int k = 0; k < KNN; k++) {
            int ix = pub[r * 1088 + lane * KNN + k];
            float d2 = d2f(qx, qy, qz, Xs[ix], Ys[ix], Zs[ix]);
            ull key = ((ull)__float_as_uint(d2) << 32) | (unsigned)ix;
            bool ins = key < maxv;
            if (__any(ins)) insertp(key, ins, k17, maxv, maxp);
        }
    }
    // round 2: 2->0, 6->4 (regions 0,1)
    __syncthreads();
    if (wv == 2 || wv == 6) {
#pragma unroll
        for (int k = 0; k < KNN; k++)
            pub[(wv >> 2) * 1088 + lane * KNN + k] = (unsigned short)(k17[k] & 0xffffULL);
    }
    __syncthreads();
    if (wv == 0 || wv == 4) {
        int r = wv >> 2;
#pragma unroll
        for (int k = 0; k < KNN; k++) {
            int ix = pub[r * 1088 + lane * KNN + k];
            float d2 = d2f(qx, qy, qz, Xs[ix], Ys[ix], Zs[ix]);
            ull key = ((ull)__float_as_uint(d2) << 32) | (unsigned)ix;
            bool ins = key < maxv;
            if (__any(ins)) insertp(key, ins, k17, maxv, maxp);
        }
    }
    // round 3: 4->0 (region 0)
    __syncthreads();
    if (wv == 4) {
#pragma unroll
        for (int k = 0; k < KNN; k++)
            pub[lane * KNN + k] = (unsigned short)(k17[k] & 0xffffULL);
    }
    __syncthreads();

    // ---- epilogue on wave 0: final merge + moments -> curv, rasig2 --------
    if (wv == 0) {
#pragma unroll
        for (int k = 0; k < KNN; k++) {
            int ix = pub[lane * KNN + k];
            float d2 = d2f(qx, qy, qz, Xs[ix], Ys[ix], Zs[ix]);
            ull key = ((ull)__float_as_uint(d2) << 32) | (unsigned)ix;
            bool ins = key < maxv;
            if (__any(ins)) insertp(key, ins, k17, maxv, maxp);
        }

        float s1x = 0, s1y = 0, s1z = 0;
        float cxx = 0, cxy = 0, cxz = 0, cyy = 0, cyz = 0, czz = 0;
#pragma unroll
        for (int k = 0; k < KNN; k++) {
            int j = (int)(k17[k] & 0xffffffffULL);
            float ux = Xs[j] - qx, uy = Ys[j] - qy, uz = Zs[j] - qz;
            s1x += ux; s1y += uy; s1z += uz;
            cxx += ux * ux; cxy += ux * uy; cxz += ux * uz;
            cyy += uy * uy; cyz += uy * uz; czz += uz * uz;
        }
        const float i16 = 1.0f / 16.0f, i15 = 1.0f / 15.0f;
        float mx = s1x * i16, my = s1y * i16, mz = s1z * i16;
        float c00 = (cxx - 16.0f * mx * mx) * i15;
        float c01 = (cxy - 16.0f * mx * my) * i15;
        float c02 = (cxz - 16.0f * mx * mz) * i15;
        float c11 = (cyy - 16.0f * my * my) * i15;
        float c12 = (cyz - 16.0f * my * mz) * i15;
        float c22 = (czz - 16.0f * mz * mz) * i15;

        float curv = curv_from_cov(c00, c01, c02, c11, c12, c22);

        float v0 = c00 > 0.0f ? c00 : 0.0f;
        float v1 = c11 > 0.0f ? c11 : 0.0f;
        float v2 = c22 > 0.0f ? c22 : 0.0f;
        float r2x = 1.0f / (0.3f * (1.0f + sqrtf(v0)) + 1e-6f);
        float r2y = 1.0f / (0.3f * (1.0f + sqrtf(v1)) + 1e-6f);
        float r2z = 1.0f / (0.3f * (1.0f + sqrtf(v2)) + 1e-6f);

        int g = b * NPTS + i;
        ws[WS_CURV + g] = curv;
        ws[WS_RAS2 + 0 * 32768 + g] = r2x;
        ws[WS_RAS2 + 1 * 32768 + g] = r2y;
        ws[WS_RAS2 + 2 * 32768 + g] = r2z;

        // non-atomic per-(b,chunk) partial sum
        float cs = curv;
        for (int off = 32; off > 0; off >>= 1) cs += __shfl_down(cs, off);
        if (lane == 0) ws[WS_CSUM + b * 64 + chunk] = cs;
    }
}

// ---------------- final embedding (lean prefix, float4 stores) -------------
__global__ void out_kernel(const float* __restrict__ xyz,
                           const float* __restrict__ ws,
                           float* __restrict__ out) {
    __shared__ float sc[3];                      // rasig1, blend, 1-blend
    __shared__ float scm[8];                     // per-batch curv mean
    if (threadIdx.x < 64) {
        // gstd from double stats (24 lanes) -> sigmoid scalars
        float part = 0.0f;
        if (threadIdx.x < 24) {
            const double* st = (const double*)(ws + WS_STAT);
            int bb = threadIdx.x / 3, dd = threadIdx.x % 3;
            double s = st[bb * 6 + dd], ss = st[bb * 6 + 3 + dd];
            double var = (ss - s * s / 4096.0) / 4095.0;
            part = (float)sqrt(var > 0.0 ? var : 0.0);
        }
        float p2 = part;
        for (int off = 32; off > 0; off >>= 1) p2 += __shfl_down(p2, off);
        if (threadIdx.x == 0) {
            float gf = p2 * (1.0f / 24.0f);
            float denom = 0.3f * (1.0f + gf) + 1e-6f;
            float blend = 1.0f / (1.0f + __expf(-(gf - 0.1f) * 10.0f));
            sc[0] = 1.0f / denom;
            sc[1] = blend;
            sc[2] = 1.0f - blend;
        }
        // per-batch curv means from 512 partials: lane L sums [L*8, L*8+8)
        float cp = 0.0f;
        const float* pf = ws + WS_CSUM;
#pragma unroll
        for (int t = 0; t < 8; t++) cp += pf[threadIdx.x * 8 + t];
        cp += __shfl_down(cp, 4);
        cp += __shfl_down(cp, 2);
        cp += __shfl_down(cp, 1);
        if ((threadIdx.x & 7) == 0) scm[threadIdx.x >> 3] = cp * (1.0f / 4096.0f);
    }
    __syncthreads();

    int q4 = blockIdx.x * 256 + (int)threadIdx.x;     // quad id (4 outputs)
    int j0 = (q4 & 31) << 2;                          // 32 quads per point
    int g  = q4 >> 5;
    int b  = g >> 12;
    float rasig1 = sc[0];
    float blend  = sc[1];
    float blendc = sc[2];
    float curv   = ws[WS_CURV + g];
    float w = 1.0f / (1.0f + __expf(-10.0f * (curv - scm[b])));
    float wc = 1.0f - w;

    float o[4];
#pragma unroll
    for (int e = 0; e < 4; e++) {
        int j = j0 + e;
        int f = (j < 127) ? j : 128;                  // OUT_IDX
        int d = (f >= 86) ? 2 : ((f >= 43) ? 1 : 0);
        int t = f - d * 43;
        float fv = (float)((double)(t + 1) * (2.0 / 44.0) - 1.0);  // FEAT_VAL
        float x = xyz[g * 3 + d];
        float t1 = (x - fv) * rasig1;
        float e1 = blend * __expf(-0.5f * t1 * t1) + blendc * __cosf(t1);
        float t2 = (x - fv) * ws[WS_RAS2 + (d << 15) + g];
        float e2 = __expf(-0.5f * t2 * t2);
        o[e] = w * e1 + wc * e2;
    }
    *(float4*)(out + ((long)q4 << 2)) = make_float4(o[0], o[1], o[2], o[3]);
}

extern "C" void kernel_launch(void* const* d_in, const int* in_sizes, int n_in,
                              void* d_out, int out_size, void* d_ws, size_t ws_size,
                              hipStream_t stream) {
    const float* xyz = (const float*)d_in[0];
    float* out = (float*)d_out;
    float* ws = (float*)d_ws;

    knn_kernel<<<512, BLKT, 0, stream>>>(xyz, ws);
    // each block writes 256 threads x 4 floats = 1024 floats
    out_kernel<<<out_size / 1024, 256, 0, stream>>>(xyz, ws, out);
}

// Round 13
// 247.363 us; speedup vs baseline: 1.0142x; 1.0138x over previous
//
#include <hip/hip_runtime.h>
#include <math.h>

// ---------------------------------------------------------------------------
// EncoderGPECls: kNN(16) -> PCA curvature blend -> adaptive GPE embeddings
// xyz: [8,4096,3] f32  ->  out: [8,4096,128] f32
//
// R25 = R20 (session best 244.8us) + inline-asm-pinned LDS pipeline.
//   R16/R20/R22/R24 ledger: compiler collapses every source-level pipeline
//   (VGPR pinned at 52 each time); both pipes <50% busy; wall ~198us is a
//   lgkmcnt queueing feedback (shallow load bursts, all waves block).
//   Fix (guide rule #18 mechanism): asm volatile ds_read_b128 groups +
//   asm volatile s_waitcnt lgkmcnt(0) + sched_barrier(0) fences around the
//   compute region. Volatile asm is mutually ordered -> 8 loads genuinely
//   in flight under each ~336cyc ladder (pass 1; depth 4 in pass 2).
//   Engagement signature: VGPR_Count 52 -> ~95-115.
//   Loads read identical bits -> selection semantics bit-identical to R20
//   (premultiplied d2p 3-fma chain everywhere, encf keys, exact tau, SCAP
//   clamp drops latest tie = jax drop, lower-index tie-break).
//
// ws float layout:
//   [0, 32768)            curv per point
//   [32768, 131072)       rasig2 (3 SoA planes of 32768)
//   [131072, 131584)      curv partial sums [b][chunk] (8 x 64)
//   [131584, 131680)      per-batch raw sums as 48 DOUBLES
// ---------------------------------------------------------------------------

#define NPTS 4096
#define KNN 17          // 16 neighbors + self (self contributes zero to sums)
#define BLKT 512        // 8 waves; 64 queries per block (1 per lane)
#define QPB 64
#define ESIZE 512       // candidates per wave (eighth)
#define SEG 256         // pass-2 segment size (u8 offsets)
#define SCAP 17         // survivor slots per lane per segment

#define WS_CURV  0
#define WS_RAS2  32768
#define WS_CSUM  131072
#define WS_STAT  131584

typedef unsigned long long ull;
typedef float f32x4 __attribute__((ext_vector_type(4)));
#define SENT 0xFFFFFFFFFFFFFFFFULL

#define SBAR()  __builtin_amdgcn_sched_barrier(0)
#define WAIT0() asm volatile("s_waitcnt lgkmcnt(0)" ::: "memory")

// 8-candidate group load: 8 x ds_read_b128 from one base VGPR + imm offsets
#define DSR8(R, ADDR) do { unsigned _a = (ADDR); \
    asm volatile("ds_read_b128 %0, %1 offset:0"   : "=v"((R)[0]) : "v"(_a)); \
    asm volatile("ds_read_b128 %0, %1 offset:16"  : "=v"((R)[1]) : "v"(_a)); \
    asm volatile("ds_read_b128 %0, %1 offset:32"  : "=v"((R)[2]) : "v"(_a)); \
    asm volatile("ds_read_b128 %0, %1 offset:48"  : "=v"((R)[3]) : "v"(_a)); \
    asm volatile("ds_read_b128 %0, %1 offset:64"  : "=v"((R)[4]) : "v"(_a)); \
    asm volatile("ds_read_b128 %0, %1 offset:80"  : "=v"((R)[5]) : "v"(_a)); \
    asm volatile("ds_read_b128 %0, %1 offset:96"  : "=v"((R)[6]) : "v"(_a)); \
    asm volatile("ds_read_b128 %0, %1 offset:112" : "=v"((R)[7]) : "v"(_a)); \
} while (0)

#define DSR4(R, ADDR) do { unsigned _a = (ADDR); \
    asm volatile("ds_read_b128 %0, %1 offset:0"   : "=v"((R)[0]) : "v"(_a)); \
    asm volatile("ds_read_b128 %0, %1 offset:16"  : "=v"((R)[1]) : "v"(_a)); \
    asm volatile("ds_read_b128 %0, %1 offset:32"  : "=v"((R)[2]) : "v"(_a)); \
    asm volatile("ds_read_b128 %0, %1 offset:48"  : "=v"((R)[3]) : "v"(_a)); \
} while (0)

// THE single d2' definition: explicit fmaf chain, identical IEEE ops at every
// call site. c = (-2cx,-2cy,-2cz,|c|^2), q = original coords.
__device__ __forceinline__ float d2p(float4 c, float qx, float qy, float qz) {
    return __builtin_fmaf(c.x, qx, __builtin_fmaf(c.y, qy,
           __builtin_fmaf(c.z, qz, c.w)));
}
// identical chain for asm-loaded vectors (same IEEE ops, same order)
__device__ __forceinline__ float d2pv(f32x4 c, float qx, float qy, float qz) {
    return __builtin_fmaf(c[0], qx, __builtin_fmaf(c[1], qy,
           __builtin_fmaf(c[2], qz, c[3])));
}

// order-preserving u32 encoding of a (possibly negative) float
__device__ __forceinline__ unsigned encf(float f) {
    unsigned u = __float_as_uint(f);
    return u ^ (unsigned)(((int)u >> 31) | 0x80000000u);
}

// predicated replace-max insert of packed (enc(d2')<<32|idx) key
__device__ __forceinline__ void insertp(ull v, bool ins, ull (&md)[KNN],
                                        ull& maxv, int& maxp) {
#pragma unroll
    for (int k = 0; k < KNN; k++) {
        bool sel = ins && (k == maxp);
        md[k] = sel ? v : md[k];
    }
    maxv = md[0]; maxp = 0;
#pragma unroll
    for (int k = 1; k < KNN; k++) {
        bool g = md[k] > maxv;
        maxv = g ? md[k] : maxv;
        maxp = g ? k : maxp;
    }
}

// ---------------- 3x3 symmetric eigensolve (double, trig method) -----------
__device__ __forceinline__ float curv_from_cov(float c00, float c01, float c02,
                                               float c11, float c12, float c22) {
    double a00 = c00, a01 = c01, a02 = c02, a11 = c11, a12 = c12, a22 = c22;
    double tr = a00 + a11 + a22;
    double q  = tr * (1.0 / 3.0);
    double b00 = a00 - q, b11 = a11 - q, b22 = a22 - q;
    double p2 = b00 * b00 + b11 * b11 + b22 * b22
              + 2.0 * (a01 * a01 + a02 * a02 + a12 * a12);
    double lmin;
    if (p2 < 1e-60) {
        lmin = q;
    } else {
        double p  = sqrt(p2 * (1.0 / 6.0));
        double ip = 1.0 / p;
        double m00 = b00 * ip, m11 = b11 * ip, m22 = b22 * ip;
        double m01 = a01 * ip, m02 = a02 * ip, m12 = a12 * ip;
        double det = m00 * (m11 * m22 - m12 * m12)
                   - m01 * (m01 * m22 - m12 * m02)
                   + m02 * (m01 * m12 - m11 * m02);
        double r = 0.5 * det;
        r = r > 1.0 ? 1.0 : (r < -1.0 ? -1.0 : r);
        double phi = acos(r) * (1.0 / 3.0);
        lmin = q + 2.0 * p * cos(phi + 2.0943951023931953);
    }
    return (float)(lmin / (tr + 1e-6));
}

// ---------------- kNN + covariance + curvature + lstd ----------------------
__global__ __launch_bounds__(BLKT, 4) void knn_kernel(const float* __restrict__ xyz,
                                                      float* __restrict__ ws) {
    __shared__ float4 pts[NPTS];                 // 64 KB premultiplied tile
    __shared__ ull aux[1088];                    // 8704 B arena (aliased)
    unsigned char* sbuf = (unsigned char*)aux;   // [SCAP][BLKT] u8 survivors
    unsigned short* pub = (unsigned short*)aux;  // 4 regions x 64x17 u16 idx
    int b = blockIdx.x >> 6;                     // 64 blocks per batch
    int chunk = blockIdx.x & 63;
    int tid = threadIdx.x;
    const float* base = xyz + b * NPTS * 3;
    for (int p = tid; p < NPTS; p += BLKT) {
        float x = base[p * 3], y = base[p * 3 + 1], z = base[p * 3 + 2];
        float w = __builtin_fmaf(z, z, __builtin_fmaf(y, y, x * x));
        pts[p] = make_float4(-2.0f * x, -2.0f * y, -2.0f * z, w);
    }
    __syncthreads();

    // ---- chunk-0 block computes per-batch raw sums in double (into aux) ----
    if (chunk == 0) {
        double sx = 0, sy = 0, sz = 0, qxx = 0, qyy = 0, qzz = 0;
        for (int p = tid; p < NPTS; p += BLKT) {
            float4 c = pts[p];
            float x = -0.5f * c.x, y = -0.5f * c.y, z = -0.5f * c.z; // exact
            sx += (double)x; sy += (double)y; sz += (double)z;
            qxx += (double)x * x; qyy += (double)y * y; qzz += (double)z * z;
        }
        for (int off = 32; off > 0; off >>= 1) {
            sx += __shfl_down(sx, off);  sy += __shfl_down(sy, off);
            sz += __shfl_down(sz, off);  qxx += __shfl_down(qxx, off);
            qyy += __shfl_down(qyy, off); qzz += __shfl_down(qzz, off);
        }
        double* dstat = (double*)aux;
        int wid = tid >> 6;
        if ((tid & 63) == 0) {
            dstat[wid * 6 + 0] = sx;  dstat[wid * 6 + 1] = sy;  dstat[wid * 6 + 2] = sz;
            dstat[wid * 6 + 3] = qxx; dstat[wid * 6 + 4] = qyy; dstat[wid * 6 + 5] = qzz;
        }
        __syncthreads();
        if (tid == 0) {
            double* wd = (double*)(ws + WS_STAT);
            for (int qq = 0; qq < 6; qq++) {
                double a = 0.0;
                for (int w = 0; w < 8; w++) a += dstat[w * 6 + qq];
                wd[b * 6 + qq] = a;
            }
        }
        __syncthreads();                         // aux free for survivor use
    }

    int wv = tid >> 6;                           // wave id: candidate eighth
    int lane = tid & 63;
    int i = chunk * QPB + lane;                  // this lane's query point
    float4 qc = pts[i];
    float qx = -0.5f * qc.x, qy = -0.5f * qc.y, qz = -0.5f * qc.z;  // exact
    int cbase = wv * ESIZE;                      // this wave's candidate range
    unsigned pb = (unsigned)(unsigned long long)&pts[cbase];  // LDS byte addr

    // ---- pass 1: med3 top-17 ladder, asm-pinned depth-8 pipeline ----------
    float md[KNN];
#pragma unroll
    for (int k = 0; k < KNN; k++) md[k] = 3.4e38f;

#define LADDER8(R) { _Pragma("unroll") \
    for (int u = 0; u < 8; u++) { \
        float d2 = d2pv((R)[u], qx, qy, qz); \
        _Pragma("unroll") \
        for (int k = KNN - 1; k >= 1; k--) \
            md[k] = __builtin_amdgcn_fmed3f(d2, md[k - 1], md[k]); \
        md[0] = fminf(d2, md[0]); } }

    {
        f32x4 A[8], B[8];
        DSR8(A, pb);
        WAIT0();
        for (int m = 0; m < ESIZE - 16; m += 16) {
            DSR8(B, pb + (unsigned)(m + 8) * 16);   // 8 in flight over ladder(A)
            SBAR();
            LADDER8(A);
            SBAR();
            WAIT0();                                 // B ready
            DSR8(A, pb + (unsigned)(m + 16) * 16);  // 8 in flight over ladder(B)
            SBAR();
            LADDER8(B);
            SBAR();
            WAIT0();                                 // A' ready
        }
        DSR8(B, pb + (unsigned)(ESIZE - 8) * 16);
        SBAR();
        LADDER8(A);
        SBAR();
        WAIT0();
        LADDER8(B);
    }
#undef LADDER8
    float tau = md[KNN - 1];   // exact 17th (identical fmaf chain everywhere)

    // ---- pass 2 (2 segments of 256): u8 survivors, asm-pinned depth-4 -----
    ull k17[KNN];
#pragma unroll
    for (int k = 0; k < KNN; k++) k17[k] = SENT;
    ull maxv = SENT; int maxp = 0;

#define P2G4(R, mo) { _Pragma("unroll") \
    for (int u = 0; u < 4; u++) { \
        float d2 = d2pv((R)[u], qx, qy, qz); \
        if (d2 <= tau) {                 /* clamp drops latest tie = jax */ \
            if (cnt < SCAP) sbuf[cnt * BLKT + tid] = (unsigned char)((mo) + u); \
            cnt++; } } }

#pragma unroll
    for (int sgi = 0; sgi < 2; sgi++) {
        int segbase = cbase + sgi * SEG;
        unsigned sb = pb + (unsigned)(sgi * SEG) * 16;
        int cnt = 0;
        {
            f32x4 A[4], B[4];
            DSR4(A, sb);
            WAIT0();
            for (int m = 0; m < SEG - 8; m += 8) {
                DSR4(B, sb + (unsigned)(m + 4) * 16);
                SBAR();
                P2G4(A, m);
                SBAR();
                WAIT0();
                DSR4(A, sb + (unsigned)(m + 8) * 16);
                SBAR();
                P2G4(B, m + 4);
                SBAR();
                WAIT0();
            }
            DSR4(B, sb + (unsigned)(SEG - 4) * 16);
            SBAR();
            P2G4(A, SEG - 8);
            SBAR();
            WAIT0();
            P2G4(B, SEG - 4);
        }
        // drain this segment's survivors into the exact u64 top-17
#pragma unroll
        for (int t = 0; t < SCAP; t++) {
            if (__any(t < cnt)) {
                int ix = segbase + sbuf[t * BLKT + tid];
                float4 c = pts[ix];
                float d2 = d2p(c, qx, qy, qz);
                ull key = ((ull)encf(d2) << 32) | (unsigned)ix;
                bool ins = (t < cnt) && (key < maxv);
                if (__any(ins)) insertp(key, ins, k17, maxv, maxp);
            }
        }
    }
#undef P2G4

    // ---- 3-round tournament merge (u16 idx publish, keys rebuilt exactly) --
    // regions: r * 1088 u16 entries, entry lane*17+k
    __syncthreads();
    if (wv & 1) {
#pragma unroll
        for (int k = 0; k < KNN; k++)
            pub[(wv >> 1) * 1088 + lane * KNN + k] = (unsigned short)(k17[k] & 0xffffULL);
    }
    __syncthreads();
    if (!(wv & 1)) {
        int r = wv >> 1;
#pragma unroll
        for (int k = 0; k < KNN; k++) {
            int ix = pub[r * 1088 + lane * KNN + k];
            float4 c = pts[ix];
            float d2 = d2p(c, qx, qy, qz);
            ull key = ((ull)encf(d2) << 32) | (unsigned)ix;
            bool ins = key < maxv;
            if (__any(ins)) insertp(key, ins, k17, maxv, maxp);
        }
    }
    // round 2: 2->0, 6->4 (regions 0,1)
    __syncthreads();
    if (wv == 2 || wv == 6) {
#pragma unroll
        for (int k = 0; k < KNN; k++)
            pub[(wv >> 2) * 1088 + lane * KNN + k] = (unsigned short)(k17[k] & 0xffffULL);
    }
    __syncthreads();
    if (wv == 0 || wv == 4) {
        int r = wv >> 2;
#pragma unroll
        for (int k = 0; k < KNN; k++) {
            int ix = pub[r * 1088 + lane * KNN + k];
            float4 c = pts[ix];
            float d2 = d2p(c, qx, qy, qz);
            ull key = ((ull)encf(d2) << 32) | (unsigned)ix;
            bool ins = key < maxv;
            if (__any(ins)) insertp(key, ins, k17, maxv, maxp);
        }
    }
    // round 3: 4->0 (region 0)
    __syncthreads();
    if (wv == 4) {
#pragma unroll
        for (int k = 0; k < KNN; k++)
            pub[lane * KNN + k] = (unsigned short)(k17[k] & 0xffffULL);
    }
    __syncthreads();

    // ---- epilogue on wave 0: final merge + moments -> curv, rasig2 --------
    if (wv == 0) {
#pragma unroll
        for (int k = 0; k < KNN; k++) {
            int ix = pub[lane * KNN + k];
            float4 c = pts[ix];
            float d2 = d2p(c, qx, qy, qz);
            ull key = ((ull)encf(d2) << 32) | (unsigned)ix;
            bool ins = key < maxv;
            if (__any(ins)) insertp(key, ins, k17, maxv, maxp);
        }

        float s1x = 0, s1y = 0, s1z = 0;
        float cxx = 0, cxy = 0, cxz = 0, cyy = 0, cyz = 0, czz = 0;
#pragma unroll
        for (int k = 0; k < KNN; k++) {
            int j = (int)(k17[k] & 0xffffffffULL);
            float4 c = pts[j];
            float ux = -0.5f * c.x - qx;         // exact original coords
            float uy = -0.5f * c.y - qy;
            float uz = -0.5f * c.z - qz;
            s1x += ux; s1y += uy; s1z += uz;
            cxx += ux * ux; cxy += ux * uy; cxz += ux * uz;
            cyy += uy * uy; cyz += uy * uz; czz += uz * uz;
        }
        const float i16 = 1.0f / 16.0f, i15 = 1.0f / 15.0f;
        float mx = s1x * i16, my = s1y * i16, mz = s1z * i16;
        float c00 = (cxx - 16.0f * mx * mx) * i15;
        float c01 = (cxy - 16.0f * mx * my) * i15;
        float c02 = (cxz - 16.0f * mx * mz) * i15;
        float c11 = (cyy - 16.0f * my * my) * i15;
        float c12 = (cyz - 16.0f * my * mz) * i15;
        float c22 = (czz - 16.0f * mz * mz) * i15;

        float curv = curv_from_cov(c00, c01, c02, c11, c12, c22);

        float v0 = c00 > 0.0f ? c00 : 0.0f;
        float v1 = c11 > 0.0f ? c11 : 0.0f;
        float v2 = c22 > 0.0f ? c22 : 0.0f;
        float r2x = 1.0f / (0.3f * (1.0f + sqrtf(v0)) + 1e-6f);
        float r2y = 1.0f / (0.3f * (1.0f + sqrtf(v1)) + 1e-6f);
        float r2z = 1.0f / (0.3f * (1.0f + sqrtf(v2)) + 1e-6f);

        int g = b * NPTS + i;
        ws[WS_CURV + g] = curv;
        ws[WS_RAS2 + 0 * 32768 + g] = r2x;
        ws[WS_RAS2 + 1 * 32768 + g] = r2y;
        ws[WS_RAS2 + 2 * 32768 + g] = r2z;

        // non-atomic per-(b,chunk) partial sum
        float cs = curv;
        for (int off = 32; off > 0; off >>= 1) cs += __shfl_down(cs, off);
        if (lane == 0) ws[WS_CSUM + b * 64 + chunk] = cs;
    }
}

// ---------------- final embedding (lean prefix, float4 stores) -------------
__global__ void out_kernel(const float* __restrict__ xyz,
                           const float* __restrict__ ws,
                           float* __restrict__ out) {
    __shared__ float sc[3];                      // rasig1, blend, 1-blend
    __shared__ float scm[8];                     // per-batch curv mean
    if (threadIdx.x < 64) {
        // gstd from double stats (24 lanes) -> sigmoid scalars
        float part = 0.0f;
        if (threadIdx.x < 24) {
            const double* st = (const double*)(ws + WS_STAT);
            int bb = threadIdx.x / 3, dd = threadIdx.x % 3;
            double s = st[bb * 6 + dd], ss = st[bb * 6 + 3 + dd];
            double var = (ss - s * s / 4096.0) / 4095.0;
            part = (float)sqrt(var > 0.0 ? var : 0.0);
        }
        float p2 = part;
        for (int off = 32; off > 0; off >>= 1) p2 += __shfl_down(p2, off);
        if (threadIdx.x == 0) {
            float gf = p2 * (1.0f / 24.0f);
            float denom = 0.3f * (1.0f + gf) + 1e-6f;
            float blend = 1.0f / (1.0f + __expf(-(gf - 0.1f) * 10.0f));
            sc[0] = 1.0f / denom;
            sc[1] = blend;
            sc[2] = 1.0f - blend;
        }
        // per-batch curv means from 512 partials: lane L sums [L*8, L*8+8)
        float cp = 0.0f;
        const float* pf = ws + WS_CSUM;
#pragma unroll
        for (int t = 0; t < 8; t++) cp += pf[threadIdx.x * 8 + t];
        cp += __shfl_down(cp, 4);
        cp += __shfl_down(cp, 2);
        cp += __shfl_down(cp, 1);
        if ((threadIdx.x & 7) == 0) scm[threadIdx.x >> 3] = cp * (1.0f / 4096.0f);
    }
    __syncthreads();

    int q4 = blockIdx.x * 256 + (int)threadIdx.x;     // quad id (4 outputs)
    int j0 = (q4 & 31) << 2;                          // 32 quads per point
    int g  = q4 >> 5;
    int b  = g >> 12;
    float rasig1 = sc[0];
    float blend  = sc[1];
    float blendc = sc[2];
    float curv   = ws[WS_CURV + g];
    float w = 1.0f / (1.0f + __expf(-10.0f * (curv - scm[b])));
    float wc = 1.0f - w;

    float o[4];
#pragma unroll
    for (int e = 0; e < 4; e++) {
        int j = j0 + e;
        int f = (j < 127) ? j : 128;                  // OUT_IDX
        int d = (f >= 86) ? 2 : ((f >= 43) ? 1 : 0);
        int t = f - d * 43;
        float fv = (float)((double)(t + 1) * (2.0 / 44.0) - 1.0);  // FEAT_VAL
        float x = xyz[g * 3 + d];
        float t1 = (x - fv) * rasig1;
        float e1 = blend * __expf(-0.5f * t1 * t1) + blendc * __cosf(t1);
        float t2 = (x - fv) * ws[WS_RAS2 + (d << 15) + g];
        float e2 = __expf(-0.5f * t2 * t2);
        o[e] = w * e1 + wc * e2;
    }
    *(float4*)(out + ((long)q4 << 2)) = make_float4(o[0], o[1], o[2], o[3]);
}

extern "C" void kernel_launch(void* const* d_in, const int* in_sizes, int n_in,
                              void* d_out, int out_size, void* d_ws, size_t ws_size,
                              hipStream_t stream) {
    const float* xyz = (const float*)d_in[0];
    float* out = (float*)d_out;
    float* ws = (float*)d_ws;

    knn_kernel<<<512, BLKT, 0, stream>>>(xyz, ws);
    // each block writes 256 threads x 4 floats = 1024 floats
    out_kernel<<<out_size / 1024, 256, 0, stream>>>(xyz, ws, out);
}

// Round 14
// 198.742 us; speedup vs baseline: 1.2623x; 1.2446x over previous
//
#include <hip/hip_runtime.h>
#include <math.h>

// ---------------------------------------------------------------------------
// EncoderGPECls: kNN(16) -> PCA curvature blend -> adaptive GPE embeddings
// xyz: [8,4096,3] f32  ->  out: [8,4096,128] f32
//
// R26 = single-pass selection: index packed into the ladder key.
//   R16/R22/R23/R24/R25 ledger: every scheduling/occupancy/stream lever is
//   null; only WORK REMOVAL ever moved knn (R20 -7%). Pass 2 + drain are
//   ~35% of instructions and ~50% of LDS ops, existing only because the
//   float med3 ladder loses indices. Fix:
//   key_u32 = (d2_bits & ~0x1FF) | idx9  (idx9 = offset in the wave's
//   512-partition). d2 >= 0 -> bit order = value order -> INTEGER ladder
//   via v_med3_u32 (gfx9-family VOP3; integer compare: no denorm/flush
//   hazards; self d2=0 -> key=idx9 ranks first; exact-duplicate ties break
//   by lower index = jax). One pass keeps top-17 WITH indices: pass 2,
//   tau, sbuf, divergent drain all deleted.
//   After the scan each wave rebuilds EXACT u64 keys (full-precision d2f +
//   global idx) and the merge tree + epilogue are byte-identical to the
//   proven R12/R24 path -> global selection exact given partition lists.
//   Only approximation: intra-partition rank-17 collisions within 2^-14
//   relative d2 (physically near-identical neighbors; negligible).
//
// ws float layout:
//   [0, 32768)            curv per point
//   [32768, 131072)       rasig2 (3 SoA planes of 32768)
//   [131072, 131584)      curv partial sums [b][chunk] (8 x 64)
//   [131584, 131680)      per-batch raw sums as 48 DOUBLES
// ---------------------------------------------------------------------------

#define NPTS 4096
#define KNN 17          // 16 neighbors + self (self contributes zero to sums)
#define BLKT 512        // 8 waves; 64 queries per block (1 per lane)
#define QPB 64
#define ESIZE 512       // candidates per wave (eighth)

#define WS_CURV  0
#define WS_RAS2  32768
#define WS_CSUM  131072
#define WS_STAT  131584

typedef unsigned long long ull;

// THE single d2 definition: explicit fmaf chain, identical IEEE ops at every
// call site (R12's proven chain; d2 >= 0 always).
__device__ __forceinline__ float d2f(float qx, float qy, float qz,
                                     float cx, float cy, float cz) {
    float dx = qx - cx, dy = qy - cy, dz = qz - cz;
    return __builtin_fmaf(dz, dz, __builtin_fmaf(dy, dy, dx * dx));
}

// integer median-of-3 (unsigned) -- the ladder primitive
__device__ __forceinline__ unsigned med3u(unsigned a, unsigned b, unsigned c) {
    unsigned d;
    asm("v_med3_u32 %0, %1, %2, %3" : "=v"(d) : "v"(a), "v"(b), "v"(c));
    return d;
}

// predicated replace-max insert of packed (d2bits<<32|idx) key
__device__ __forceinline__ void insertp(ull v, bool ins, ull (&md)[KNN],
                                        ull& maxv, int& maxp) {
#pragma unroll
    for (int k = 0; k < KNN; k++) {
        bool sel = ins && (k == maxp);
        md[k] = sel ? v : md[k];
    }
    maxv = md[0]; maxp = 0;
#pragma unroll
    for (int k = 1; k < KNN; k++) {
        bool g = md[k] > maxv;
        maxv = g ? md[k] : maxv;
        maxp = g ? k : maxp;
    }
}

// ---------------- 3x3 symmetric eigensolve (double, trig method) -----------
__device__ __forceinline__ float curv_from_cov(float c00, float c01, float c02,
                                               float c11, float c12, float c22) {
    double a00 = c00, a01 = c01, a02 = c02, a11 = c11, a12 = c12, a22 = c22;
    double tr = a00 + a11 + a22;
    double q  = tr * (1.0 / 3.0);
    double b00 = a00 - q, b11 = a11 - q, b22 = a22 - q;
    double p2 = b00 * b00 + b11 * b11 + b22 * b22
              + 2.0 * (a01 * a01 + a02 * a02 + a12 * a12);
    double lmin;
    if (p2 < 1e-60) {
        lmin = q;
    } else {
        double p  = sqrt(p2 * (1.0 / 6.0));
        double ip = 1.0 / p;
        double m00 = b00 * ip, m11 = b11 * ip, m22 = b22 * ip;
        double m01 = a01 * ip, m02 = a02 * ip, m12 = a12 * ip;
        double det = m00 * (m11 * m22 - m12 * m12)
                   - m01 * (m01 * m22 - m12 * m02)
                   + m02 * (m01 * m12 - m11 * m02);
        double r = 0.5 * det;
        r = r > 1.0 ? 1.0 : (r < -1.0 ? -1.0 : r);
        double phi = acos(r) * (1.0 / 3.0);
        lmin = q + 2.0 * p * cos(phi + 2.0943951023931953);
    }
    return (float)(lmin / (tr + 1e-6));
}

// ---------------- kNN + covariance + curvature + lstd ----------------------
__global__ __launch_bounds__(BLKT, 4) void knn_kernel(const float* __restrict__ xyz,
                                                      float* __restrict__ ws) {
    __shared__ float4 pts[NPTS];                 // 64 KB raw (x,y,z,0) tile
    __shared__ ull aux[1088];                    // 8704 B arena (aliased)
    unsigned short* pub = (unsigned short*)aux;  // 4 regions x 64x17 u16 idx
    int b = blockIdx.x >> 6;                     // 64 blocks per batch
    int chunk = blockIdx.x & 63;
    int tid = threadIdx.x;
    const float* base = xyz + b * NPTS * 3;
    for (int p = tid; p < NPTS; p += BLKT) {
        pts[p] = make_float4(base[p * 3], base[p * 3 + 1], base[p * 3 + 2], 0.0f);
    }
    __syncthreads();

    // ---- chunk-0 block computes per-batch raw sums in double (into aux) ----
    if (chunk == 0) {
        double sx = 0, sy = 0, sz = 0, qxx = 0, qyy = 0, qzz = 0;
        for (int p = tid; p < NPTS; p += BLKT) {
            float4 c = pts[p];
            sx += (double)c.x; sy += (double)c.y; sz += (double)c.z;
            qxx += (double)c.x * c.x; qyy += (double)c.y * c.y; qzz += (double)c.z * c.z;
        }
        for (int off = 32; off > 0; off >>= 1) {
            sx += __shfl_down(sx, off);  sy += __shfl_down(sy, off);
            sz += __shfl_down(sz, off);  qxx += __shfl_down(qxx, off);
            qyy += __shfl_down(qyy, off); qzz += __shfl_down(qzz, off);
        }
        double* dstat = (double*)aux;
        int wid = tid >> 6;
        if ((tid & 63) == 0) {
            dstat[wid * 6 + 0] = sx;  dstat[wid * 6 + 1] = sy;  dstat[wid * 6 + 2] = sz;
            dstat[wid * 6 + 3] = qxx; dstat[wid * 6 + 4] = qyy; dstat[wid * 6 + 5] = qzz;
        }
        __syncthreads();
        if (tid == 0) {
            double* wd = (double*)(ws + WS_STAT);
            for (int qq = 0; qq < 6; qq++) {
                double a = 0.0;
                for (int w = 0; w < 8; w++) a += dstat[w * 6 + qq];
                wd[b * 6 + qq] = a;
            }
        }
        __syncthreads();                         // aux free for pub use
    }

    int wv = tid >> 6;                           // wave id: candidate eighth
    int lane = tid & 63;
    int i = chunk * QPB + lane;                  // this lane's query point
    float4 qc = pts[i];
    float qx = qc.x, qy = qc.y, qz = qc.z;
    int cbase = wv * ESIZE;                      // this wave's candidate range

    // ---- single pass: u32 med3 ladder on (d2bits&~0x1FF)|idx9 keys --------
    unsigned kd[KNN];
#pragma unroll
    for (int k = 0; k < KNN; k++) kd[k] = 0xFFFFFFFFu;

#define LADDER(c, off) { \
    float d2 = d2f(qx, qy, qz, (c).x, (c).y, (c).z); \
    unsigned key = (__float_as_uint(d2) & 0xFFFFFE00u) | (unsigned)(off); \
    _Pragma("unroll") \
    for (int k = KNN - 1; k >= 1; k--)   /* descending: reads olds only */ \
        kd[k] = med3u(key, kd[k - 1], kd[k]); \
    kd[0] = key < kd[0] ? key : kd[0]; }

    {
        float4 A[8], B[8];
#pragma unroll
        for (int u = 0; u < 8; u++) A[u] = pts[cbase + u];
        for (int m = 0; m < ESIZE - 16; m += 16) {
#pragma unroll
            for (int u = 0; u < 8; u++) B[u] = pts[cbase + m + 8 + u];
#pragma unroll
            for (int u = 0; u < 8; u++) LADDER(A[u], m + u);
#pragma unroll
            for (int u = 0; u < 8; u++) A[u] = pts[cbase + m + 16 + u];
#pragma unroll
            for (int u = 0; u < 8; u++) LADDER(B[u], m + 8 + u);
        }
        // tail: A = [ESIZE-16, ESIZE-8), B = [ESIZE-8, ESIZE)
#pragma unroll
        for (int u = 0; u < 8; u++) B[u] = pts[cbase + ESIZE - 8 + u];
#pragma unroll
        for (int u = 0; u < 8; u++) LADDER(A[u], ESIZE - 16 + u);
#pragma unroll
        for (int u = 0; u < 8; u++) LADDER(B[u], ESIZE - 8 + u);
    }
#undef LADDER

    // ---- rebuild exact u64 keys (full-precision d2, global idx) -----------
    ull k17[KNN];
#pragma unroll
    for (int k = 0; k < KNN; k++) {
        int ix = cbase + (int)(kd[k] & 0x1FFu);
        float4 c = pts[ix];
        float d2 = d2f(qx, qy, qz, c.x, c.y, c.z);
        k17[k] = ((ull)__float_as_uint(d2) << 32) | (unsigned)ix;
    }
    ull maxv = k17[0]; int maxp = 0;
#pragma unroll
    for (int k = 1; k < KNN; k++) {
        bool g = k17[k] > maxv;
        maxv = g ? k17[k] : maxv;
        maxp = g ? k : maxp;
    }

    // ---- 3-round tournament merge (u16 idx publish, keys rebuilt exactly) --
    // regions: r * 1088 u16 entries, entry lane*17+k
    __syncthreads();
    if (wv & 1) {
#pragma unroll
        for (int k = 0; k < KNN; k++)
            pub[(wv >> 1) * 1088 + lane * KNN + k] = (unsigned short)(k17[k] & 0xffffULL);
    }
    __syncthreads();
    if (!(wv & 1)) {
        int r = wv >> 1;
#pragma unroll
        for (int k = 0; k < KNN; k++) {
            int ix = pub[r * 1088 + lane * KNN + k];
            float4 c = pts[ix];
            float d2 = d2f(qx, qy, qz, c.x, c.y, c.z);
            ull key = ((ull)__float_as_uint(d2) << 32) | (unsigned)ix;
            bool ins = key < maxv;
            if (__any(ins)) insertp(key, ins, k17, maxv, maxp);
        }
    }
    // round 2: 2->0, 6->4 (regions 0,1)
    __syncthreads();
    if (wv == 2 || wv == 6) {
#pragma unroll
        for (int k = 0; k < KNN; k++)
            pub[(wv >> 2) * 1088 + lane * KNN + k] = (unsigned short)(k17[k] & 0xffffULL);
    }
    __syncthreads();
    if (wv == 0 || wv == 4) {
        int r = wv >> 2;
#pragma unroll
        for (int k = 0; k < KNN; k++) {
            int ix = pub[r * 1088 + lane * KNN + k];
            float4 c = pts[ix];
            float d2 = d2f(qx, qy, qz, c.x, c.y, c.z);
            ull key = ((ull)__float_as_uint(d2) << 32) | (unsigned)ix;
            bool ins = key < maxv;
            if (__any(ins)) insertp(key, ins, k17, maxv, maxp);
        }
    }
    // round 3: 4->0 (region 0)
    __syncthreads();
    if (wv == 4) {
#pragma unroll
        for (int k = 0; k < KNN; k++)
            pub[lane * KNN + k] = (unsigned short)(k17[k] & 0xffffULL);
    }
    __syncthreads();

    // ---- epilogue on wave 0: final merge + moments -> curv, rasig2 --------
    if (wv == 0) {
#pragma unroll
        for (int k = 0; k < KNN; k++) {
            int ix = pub[lane * KNN + k];
            float4 c = pts[ix];
            float d2 = d2f(qx, qy, qz, c.x, c.y, c.z);
            ull key = ((ull)__float_as_uint(d2) << 32) | (unsigned)ix;
            bool ins = key < maxv;
            if (__any(ins)) insertp(key, ins, k17, maxv, maxp);
        }

        float s1x = 0, s1y = 0, s1z = 0;
        float cxx = 0, cxy = 0, cxz = 0, cyy = 0, cyz = 0, czz = 0;
#pragma unroll
        for (int k = 0; k < KNN; k++) {
            int j = (int)(k17[k] & 0xffffffffULL);
            float4 c = pts[j];
            float ux = c.x - qx, uy = c.y - qy, uz = c.z - qz;
            s1x += ux; s1y += uy; s1z += uz;
            cxx += ux * ux; cxy += ux * uy; cxz += ux * uz;
            cyy += uy * uy; cyz += uy * uz; czz += uz * uz;
        }
        const float i16 = 1.0f / 16.0f, i15 = 1.0f / 15.0f;
        float mx = s1x * i16, my = s1y * i16, mz = s1z * i16;
        float c00 = (cxx - 16.0f * mx * mx) * i15;
        float c01 = (cxy - 16.0f * mx * my) * i15;
        float c02 = (cxz - 16.0f * mx * mz) * i15;
        float c11 = (cyy - 16.0f * my * my) * i15;
        float c12 = (cyz - 16.0f * my * mz) * i15;
        float c22 = (czz - 16.0f * mz * mz) * i15;

        float curv = curv_from_cov(c00, c01, c02, c11, c12, c22);

        float v0 = c00 > 0.0f ? c00 : 0.0f;
        float v1 = c11 > 0.0f ? c11 : 0.0f;
        float v2 = c22 > 0.0f ? c22 : 0.0f;
        float r2x = 1.0f / (0.3f * (1.0f + sqrtf(v0)) + 1e-6f);
        float r2y = 1.0f / (0.3f * (1.0f + sqrtf(v1)) + 1e-6f);
        float r2z = 1.0f / (0.3f * (1.0f + sqrtf(v2)) + 1e-6f);

        int g = b * NPTS + i;
        ws[WS_CURV + g] = curv;
        ws[WS_RAS2 + 0 * 32768 + g] = r2x;
        ws[WS_RAS2 + 1 * 32768 + g] = r2y;
        ws[WS_RAS2 + 2 * 32768 + g] = r2z;

        // non-atomic per-(b,chunk) partial sum
        float cs = curv;
        for (int off = 32; off > 0; off >>= 1) cs += __shfl_down(cs, off);
        if (lane == 0) ws[WS_CSUM + b * 64 + chunk] = cs;
    }
}

// ---------------- final embedding (lean prefix, float4 stores) -------------
__global__ void out_kernel(const float* __restrict__ xyz,
                           const float* __restrict__ ws,
                           float* __restrict__ out) {
    __shared__ float sc[3];                      // rasig1, blend, 1-blend
    __shared__ float scm[8];                     // per-batch curv mean
    if (threadIdx.x < 64) {
        // gstd from double stats (24 lanes) -> sigmoid scalars
        float part = 0.0f;
        if (threadIdx.x < 24) {
            const double* st = (const double*)(ws + WS_STAT);
            int bb = threadIdx.x / 3, dd = threadIdx.x % 3;
            double s = st[bb * 6 + dd], ss = st[bb * 6 + 3 + dd];
            double var = (ss - s * s / 4096.0) / 4095.0;
            part = (float)sqrt(var > 0.0 ? var : 0.0);
        }
        float p2 = part;
        for (int off = 32; off > 0; off >>= 1) p2 += __shfl_down(p2, off);
        if (threadIdx.x == 0) {
            float gf = p2 * (1.0f / 24.0f);
            float denom = 0.3f * (1.0f + gf) + 1e-6f;
            float blend = 1.0f / (1.0f + __expf(-(gf - 0.1f) * 10.0f));
            sc[0] = 1.0f / denom;
            sc[1] = blend;
            sc[2] = 1.0f - blend;
        }
        // per-batch curv means from 512 partials: lane L sums [L*8, L*8+8)
        float cp = 0.0f;
        const float* pf = ws + WS_CSUM;
#pragma unroll
        for (int t = 0; t < 8; t++) cp += pf[threadIdx.x * 8 + t];
        cp += __shfl_down(cp, 4);
        cp += __shfl_down(cp, 2);
        cp += __shfl_down(cp, 1);
        if ((threadIdx.x & 7) == 0) scm[threadIdx.x >> 3] = cp * (1.0f / 4096.0f);
    }
    __syncthreads();

    int q4 = blockIdx.x * 256 + (int)threadIdx.x;     // quad id (4 outputs)
    int j0 = (q4 & 31) << 2;                          // 32 quads per point
    int g  = q4 >> 5;
    int b  = g >> 12;
    float rasig1 = sc[0];
    float blend  = sc[1];
    float blendc = sc[2];
    float curv   = ws[WS_CURV + g];
    float w = 1.0f / (1.0f + __expf(-10.0f * (curv - scm[b])));
    float wc = 1.0f - w;

    float o[4];
#pragma unroll
    for (int e = 0; e < 4; e++) {
        int j = j0 + e;
        int f = (j < 127) ? j : 128;                  // OUT_IDX
        int d = (f >= 86) ? 2 : ((f >= 43) ? 1 : 0);
        int t = f - d * 43;
        float fv = (float)((double)(t + 1) * (2.0 / 44.0) - 1.0);  // FEAT_VAL
        float x = xyz[g * 3 + d];
        float t1 = (x - fv) * rasig1;
        float e1 = blend * __expf(-0.5f * t1 * t1) + blendc * __cosf(t1);
        float t2 = (x - fv) * ws[WS_RAS2 + (d << 15) + g];
        float e2 = __expf(-0.5f * t2 * t2);
        o[e] = w * e1 + wc * e2;
    }
    *(float4*)(out + ((long)q4 << 2)) = make_float4(o[0], o[1], o[2], o[3]);
}

extern "C" void kernel_launch(void* const* d_in, const int* in_sizes, int n_in,
                              void* d_out, int out_size, void* d_ws, size_t ws_size,
                              hipStream_t stream) {
    const float* xyz = (const float*)d_in[0];
    float* out = (float*)d_out;
    float* ws = (float*)d_ws;

    knn_kernel<<<512, BLKT, 0, stream>>>(xyz, ws);
    // each block writes 256 threads x 4 floats = 1024 floats
    out_kernel<<<out_size / 1024, 256, 0, stream>>>(xyz, ws, out);
}